// Round 11
// baseline (258.021 us; speedup 1.0000x reference)
//
#include <hip/hip_runtime.h>

#define N_NODES 100000
#define N_EDGES 1600000
#define C 128
#define LEAKY 0.01f
#define BN_EPS 1e-5f
#define NB_C 391           // coarse buckets (dst>>8), 256 nodes each
#define PB 391             // partition blocks
#define PBLK 4096          // edges per partition block
#define STASH 8192         // fine-kernel LDS pair stash (avg bucket = 4092)
#define NBG 1563           // gemm blocks = ceil(100000/64)

typedef __attribute__((ext_vector_type(8))) short short8;   // 8 bf16 = 16B
typedef __attribute__((ext_vector_type(4))) float f32x4;

__device__ __forceinline__ unsigned short f2bf(float f) {   // RNE float->bf16
    unsigned int u = __builtin_bit_cast(unsigned int, f);
    u += 0x7FFFu + ((u >> 16) & 1u);
    return (unsigned short)(u >> 16);
}
__device__ __forceinline__ float bf2f(unsigned short b) {
    unsigned int u = ((unsigned int)b) << 16;
    return __builtin_bit_cast(float, u);
}

// ---------------------------------------------------------------- init: cast-transpose W; zero dummy xb row
__global__ __launch_bounds__(256) void k_init(const float* __restrict__ W,
                                              unsigned short* __restrict__ wt,
                                              unsigned short* __restrict__ xb) {
    int i = blockIdx.x * 256 + threadIdx.x;
    wt[i] = f2bf(W[(i & 127) * C + (i >> 7)]);   // wt[c][k] = W[k][c]
    if (i < C) xb[(size_t)N_NODES * C + i] = 0;  // zero row for tail gathers
}

// ---------------------------------------------------------------- coarse histogram: per-block counts per bucket
__global__ __launch_bounds__(256) void k_coarse(const int* __restrict__ dst,
                                                int* __restrict__ blk_cnt) {
    __shared__ int lh[NB_C];
    int tid = threadIdx.x, blk = blockIdx.x;
    for (int i = tid; i < NB_C; i += 256) lh[i] = 0;
    __syncthreads();
    #pragma unroll
    for (int it = 0; it < PBLK / 256; ++it) {
        int e = blk * PBLK + it * 256 + tid;
        if (e < N_EDGES) atomicAdd(&lh[dst[e] >> 8], 1);
    }
    __syncthreads();
    for (int i = tid; i < NB_C; i += 256) blk_cnt[i * PB + blk] = lh[i];
}

// ---------------------------------------------------------------- per-bucket exclusive scan over blocks
__global__ __launch_bounds__(512) void k_offsets(const int* __restrict__ blk_cnt,
                                                 int* __restrict__ offset,
                                                 int* __restrict__ total) {
    __shared__ int tmp[512];
    int t = threadIdx.x, k = blockIdx.x;
    int v = (t < PB) ? blk_cnt[k * PB + t] : 0;
    tmp[t] = v;
    __syncthreads();
    for (int off = 1; off < 512; off <<= 1) {
        int u = (t >= off) ? tmp[t - off] : 0;
        __syncthreads();
        tmp[t] += u;
        __syncthreads();
    }
    if (t < PB) offset[k * PB + t] = tmp[t] - v;
    if (t == 511) total[k] = tmp[511];
}

// ---------------------------------------------------------------- bucket-base scan (1 block)
__global__ __launch_bounds__(512) void k_cbase(const int* __restrict__ total,
                                               int* __restrict__ cbase,
                                               int* __restrict__ offs) {
    __shared__ int tmp[512];
    int t = threadIdx.x;
    int v = (t < NB_C) ? total[t] : 0;
    tmp[t] = v;
    __syncthreads();
    for (int off = 1; off < 512; off <<= 1) {
        int u = (t >= off) ? tmp[t - off] : 0;
        __syncthreads();
        tmp[t] += u;
        __syncthreads();
    }
    if (t < NB_C) cbase[t] = tmp[t] - v;
    if (t == 0) { cbase[NB_C] = N_EDGES; offs[N_NODES] = N_EDGES; }
}

// ---------------------------------------------------------------- partition: packed (src | dlow<<17) into bucket chunks
__global__ __launch_bounds__(256) void k_partition(const int* __restrict__ src,
                                                   const int* __restrict__ dst,
                                                   const int* __restrict__ cbase,
                                                   const int* __restrict__ offset,
                                                   unsigned int* __restrict__ pairs) {
    __shared__ int lh[NB_C];
    __shared__ int lbase[NB_C];
    int tid = threadIdx.x, blk = blockIdx.x;
    for (int i = tid; i < NB_C; i += 256) {
        lh[i] = 0;
        lbase[i] = cbase[i] + offset[i * PB + blk];
    }
    __syncthreads();
    #pragma unroll
    for (int it = 0; it < PBLK / 256; ++it) {
        int e = blk * PBLK + it * 256 + tid;
        if (e < N_EDGES) {
            int d = dst[e];
            int b = d >> 8;
            int r = atomicAdd(&lh[b], 1);
            pairs[lbase[b] + r] = (unsigned int)src[e] | ((unsigned int)(d & 255) << 17);
        }
    }
}

// ---------------------------------------------------------------- fine: per-bucket hist -> dinv+offs; LDS-rank -> srt
__global__ __launch_bounds__(256) void k_fine(const unsigned int* __restrict__ pairs,
                                              const int* __restrict__ cbase,
                                              float* __restrict__ dinv,
                                              int* __restrict__ offs,
                                              int* __restrict__ srt) {
    __shared__ int hist[256];
    __shared__ int loff[256];
    __shared__ int cnt2[256];
    __shared__ unsigned int stash[STASH];
    int tid = threadIdx.x, blk = blockIdx.x;
    int nbase = blk * 256;
    int nn = (nbase + 256 <= N_NODES) ? 256 : (N_NODES - nbase);
    int ebeg = cbase[blk];
    int ne = cbase[blk + 1] - ebeg;

    hist[tid] = 0; cnt2[tid] = 0;
    __syncthreads();
    for (int k = tid; k < ne; k += 256) {
        unsigned int pk = pairs[ebeg + k];
        if (k < STASH) stash[k] = pk;
        atomicAdd(&hist[pk >> 17], 1);
    }
    __syncthreads();
    if (tid < nn) dinv[nbase + tid] = rsqrtf((float)(hist[tid] + 1));
    // exclusive scan of hist into loff
    loff[tid] = hist[tid];
    __syncthreads();
    for (int off = 1; off < 256; off <<= 1) {
        int u = (tid >= off) ? loff[tid - off] : 0;
        __syncthreads();
        loff[tid] += u;
        __syncthreads();
    }
    loff[tid] -= hist[tid];           // exclusive
    if (tid < nn) offs[nbase + tid] = ebeg + loff[tid];
    __syncthreads();
    for (int k = tid; k < ne; k += 256) {
        unsigned int pk = (k < STASH) ? stash[k] : pairs[ebeg + k];
        int dl = pk >> 17;
        int r = atomicAdd(&cnt2[dl], 1);
        srt[ebeg + loff[dl] + r] = (int)(pk & 0x1FFFFu);
    }
}

// ---------------------------------------------------------------- cast: xb = bf16(x * dinv[row]), full grid
__global__ __launch_bounds__(256) void k_cast(const float* __restrict__ x,
                                              const float* __restrict__ dinv,
                                              unsigned short* __restrict__ xb) {
    int i = blockIdx.x * 256 + threadIdx.x;   // short8 index, N*C/8 total
    int node = i >> 4;                         // 16 short8 per row
    float dv = dinv[node];
    const float4* xp = (const float4*)(x) + (size_t)i * 2;
    float4 p0 = xp[0], p1 = xp[1];
    short8 o;
    o[0] = (short)f2bf(p0.x * dv); o[1] = (short)f2bf(p0.y * dv);
    o[2] = (short)f2bf(p0.z * dv); o[3] = (short)f2bf(p0.w * dv);
    o[4] = (short)f2bf(p1.x * dv); o[5] = (short)f2bf(p1.y * dv);
    o[6] = (short)f2bf(p1.z * dv); o[7] = (short)f2bf(p1.w * dv);
    ((short8*)xb)[i] = o;
}

// ---------------------------------------------------------------- aggregate: 16 lanes/node, short8/lane, zero-row tail
// agg[d] = bf16( dn * (xb[d] + sum_bucket xb[s]) )
__global__ __launch_bounds__(256) void k_aggregate(const short8* __restrict__ xb8,
                                                   const int* __restrict__ srt,
                                                   const int* __restrict__ offs,
                                                   const float* __restrict__ dinv,
                                                   short8* __restrict__ agg8) {
    int node = blockIdx.x * 16 + (threadIdx.x >> 4);
    int c8 = threadIdx.x & 15;

    float dn = dinv[node];
    int beg = offs[node];
    int end = offs[node + 1];

    short8 ms = xb8[(size_t)node * 16 + c8];
    float ax[8];
    #pragma unroll
    for (int ch = 0; ch < 8; ++ch) ax[ch] = bf2f((unsigned short)ms[ch]);

    for (int k = beg; k < end; k += 8) {
        int idx[8];
        #pragma unroll
        for (int i = 0; i < 8; ++i) {
            int ki = k + i;
            idx[i] = (ki < end) ? srt[ki] : N_NODES;   // dummy zero row
        }
        short8 m[8];
        #pragma unroll
        for (int i = 0; i < 8; ++i) m[i] = xb8[(size_t)idx[i] * 16 + c8];
        #pragma unroll
        for (int i = 0; i < 8; ++i)
            #pragma unroll
            for (int ch = 0; ch < 8; ++ch)
                ax[ch] += bf2f((unsigned short)m[i][ch]);
    }

    short8 o;
    #pragma unroll
    for (int ch = 0; ch < 8; ++ch) o[ch] = (short)f2bf(dn * ax[ch]);
    agg8[(size_t)node * 16 + c8] = o;
}

// ---------------------------------------------------------------- gemm pass 1: BN partials only (no out write)
__global__ __launch_bounds__(256) void k_gemm_stats(const unsigned short* __restrict__ agg,
                                                    const unsigned short* __restrict__ wt,
                                                    const float* __restrict__ bias,
                                                    float* __restrict__ part) {
    __shared__ float lsum[C], lsq[C];
    for (int i = threadIdx.x; i < C; i += 256) { lsum[i] = 0.0f; lsq[i] = 0.0f; }
    __syncthreads();

    int tile = blockIdx.x * 4 + (threadIdx.x >> 6);
    int lane = threadIdx.x & 63;
    if (tile < N_NODES / 16) {
        int row0 = tile * 16;
        int ar = lane & 15;
        int kg = (lane >> 4) * 8;

        short8 a[4];
        #pragma unroll
        for (int kk = 0; kk < 4; ++kk)
            a[kk] = *(const short8*)&agg[(size_t)(row0 + ar) * C + kk * 32 + kg];

        #pragma unroll
        for (int ct = 0; ct < 8; ++ct) {
            f32x4 acc = {0.f, 0.f, 0.f, 0.f};
            #pragma unroll
            for (int kk = 0; kk < 4; ++kk) {
                short8 b = *(const short8*)&wt[(size_t)(ct * 16 + ar) * C + kk * 32 + kg];
                acc = __builtin_amdgcn_mfma_f32_16x16x32_bf16(a[kk], b, acc, 0, 0, 0);
            }
            int col = ct * 16 + ar;      // C/D: col=lane&15, row=(lane>>4)*4+r
            float bb = bias[col];
            float s = 0.0f, q = 0.0f;
            #pragma unroll
            for (int r = 0; r < 4; ++r) {
                float v = acc[r] + bb;
                v = v > 0.0f ? v : LEAKY * v;
                s += v; q += v * v;
            }
            atomicAdd(&lsum[col], s);
            atomicAdd(&lsq[col], q);
        }
    }
    __syncthreads();
    for (int i = threadIdx.x; i < C; i += 256) {
        part[(size_t)blockIdx.x * 256 + i]       = lsum[i];
        part[(size_t)blockIdx.x * 256 + 128 + i] = lsq[i];
    }
}

// ---------------------------------------------------------------- params: reduce partials, fold BN scale/shift
__global__ __launch_bounds__(1024) void k_params(const float* __restrict__ part,
                                                 const float* __restrict__ gamma,
                                                 const float* __restrict__ beta,
                                                 float* __restrict__ scale,
                                                 float* __restrict__ shift) {
    __shared__ float rs[1024], rq[1024];
    int c = threadIdx.x & 127, g = threadIdx.x >> 7;   // 8 groups
    float s = 0.0f, q = 0.0f;
    for (int b = g; b < NBG; b += 8) {
        s += part[(size_t)b * 256 + c];
        q += part[(size_t)b * 256 + 128 + c];
    }
    rs[threadIdx.x] = s; rq[threadIdx.x] = q;
    __syncthreads();
    if (threadIdx.x < 128) {
        float S = 0.0f, Q = 0.0f;
        #pragma unroll
        for (int g2 = 0; g2 < 8; ++g2) { S += rs[g2 * 128 + c]; Q += rq[g2 * 128 + c]; }
        float inv_n = 1.0f / (float)N_NODES;
        float mean = S * inv_n;
        float var = Q * inv_n - mean * mean;
        float sc = gamma[c] * rsqrtf(var + BN_EPS);
        scale[c] = sc;
        shift[c] = beta[c] - mean * sc;
    }
}

// ---------------------------------------------------------------- gemm pass 2: recompute + fused BN apply, final out
__global__ __launch_bounds__(256) void k_gemm_apply(const unsigned short* __restrict__ agg,
                                                    const unsigned short* __restrict__ wt,
                                                    const float* __restrict__ bias,
                                                    const float* __restrict__ scale,
                                                    const float* __restrict__ shift,
                                                    float* __restrict__ out) {
    int tile = blockIdx.x * 4 + (threadIdx.x >> 6);
    if (tile >= N_NODES / 16) return;
    int lane = threadIdx.x & 63;
    int row0 = tile * 16;
    int ar = lane & 15;
    int kg = (lane >> 4) * 8;

    short8 a[4];
    #pragma unroll
    for (int kk = 0; kk < 4; ++kk)
        a[kk] = *(const short8*)&agg[(size_t)(row0 + ar) * C + kk * 32 + kg];

    int rb = (lane >> 4) * 4;
    #pragma unroll
    for (int ct = 0; ct < 8; ++ct) {
        f32x4 acc = {0.f, 0.f, 0.f, 0.f};
        #pragma unroll
        for (int kk = 0; kk < 4; ++kk) {
            short8 b = *(const short8*)&wt[(size_t)(ct * 16 + ar) * C + kk * 32 + kg];
            acc = __builtin_amdgcn_mfma_f32_16x16x32_bf16(a[kk], b, acc, 0, 0, 0);
        }
        int col = ct * 16 + ar;          // C/D: col=lane&15, row=(lane>>4)*4+r
        float bb = bias[col];
        float sc = scale[col];
        float sh = shift[col];
        #pragma unroll
        for (int r = 0; r < 4; ++r) {
            float v = acc[r] + bb;
            v = v > 0.0f ? v : LEAKY * v;
            out[(size_t)(row0 + rb + r) * C + col] = v * sc + sh;
        }
    }
}

extern "C" void kernel_launch(void* const* d_in, const int* in_sizes, int n_in,
                              void* d_out, int out_size, void* d_ws, size_t ws_size,
                              hipStream_t stream) {
    const float* x     = (const float*)d_in[0];
    const int*   edge  = (const int*)d_in[1];
    const float* W     = (const float*)d_in[2];
    const float* bias  = (const float*)d_in[3];
    const float* gamma = (const float*)d_in[4];
    const float* beta  = (const float*)d_in[5];
    float* out = (float*)d_out;
    char* ws = (char*)d_ws;

    // workspace layout (~68 MB)
    unsigned short* xb    = (unsigned short*)ws;  ws += (size_t)(N_NODES + 1) * C * 2; // 25.6 MB (+zero row)
    unsigned short* agg   = (unsigned short*)ws;  ws += (size_t)N_NODES * C * 2;       // 25.6 MB
    unsigned short* wt    = (unsigned short*)ws;  ws += (size_t)C * C * 2;             // 32 KB
    unsigned int*   pairs = (unsigned int*)ws;    ws += (size_t)N_EDGES * 4;           // 6.4 MB
    int*   srt     = (int*)ws;                    ws += (size_t)N_EDGES * 4;           // 6.4 MB
    int*   blk_cnt = (int*)ws;                    ws += (size_t)NB_C * PB * 4;         // 612 KB
    int*   offset  = (int*)ws;                    ws += (size_t)NB_C * PB * 4;         // 612 KB
    int*   total   = (int*)ws;                    ws += 512 * 4;
    int*   cbase   = (int*)ws;                    ws += 512 * 4;
    int*   offs    = (int*)ws;                    ws += (size_t)(N_NODES + 1) * 4;     // 400 KB
    float* dinv    = (float*)ws;                  ws += (size_t)N_NODES * 4;           // 400 KB
    float* part    = (float*)ws;                  ws += (size_t)NBG * 256 * 4;         // 1.6 MB
    float* scale   = (float*)ws;                  ws += C * 4;
    float* shift   = (float*)ws;

    const int* src = edge;
    const int* dst = edge + N_EDGES;

    k_init      <<<C * C / 256,           256, 0, stream>>>(W, wt, xb);
    k_coarse    <<<PB,                    256, 0, stream>>>(dst, blk_cnt);
    k_offsets   <<<NB_C,                  512, 0, stream>>>(blk_cnt, offset, total);
    k_cbase     <<<1,                     512, 0, stream>>>(total, cbase, offs);
    k_partition <<<PB,                    256, 0, stream>>>(src, dst, cbase, offset, pairs);
    k_fine      <<<NB_C,                  256, 0, stream>>>(pairs, cbase, dinv, offs, srt);
    k_cast      <<<N_NODES * C / 8 / 256, 256, 0, stream>>>(x, dinv, xb);
    k_aggregate <<<N_NODES / 16,          256, 0, stream>>>((const short8*)xb, srt, offs, dinv, (short8*)agg);
    k_gemm_stats<<<NBG,                   256, 0, stream>>>(agg, wt, bias, part);
    k_params    <<<1,                    1024, 0, stream>>>(part, gamma, beta, scale, shift);
    k_gemm_apply<<<NBG,                   256, 0, stream>>>(agg, wt, bias, scale, shift, out);
}

// Round 12
// 194.597 us; speedup vs baseline: 1.3259x; 1.3259x over previous
//
#include <hip/hip_runtime.h>

#define N_NODES 100000
#define N_EDGES 1600000
#define C 128
#define LEAKY 0.01f
#define BN_EPS 1e-5f
#define NB_C 391           // coarse buckets (dst>>8), 256 nodes each
#define PB 391             // partition blocks
#define PBLK 4096          // edges per partition block
#define STASH 8192         // fine-kernel LDS pair stash (avg bucket = 4092)
#define NBG 1563           // gemm blocks = ceil(6250 tiles / 4)
#define NAGG 6250          // aggregate blocks = N_NODES/16
#define NRED 64            // reduce blocks

typedef __attribute__((ext_vector_type(8))) short short8;   // 8 bf16 = 16B
typedef __attribute__((ext_vector_type(4))) float f32x4;

__device__ __forceinline__ unsigned short f2bf(float f) {   // RNE float->bf16
    unsigned int u = __builtin_bit_cast(unsigned int, f);
    u += 0x7FFFu + ((u >> 16) & 1u);
    return (unsigned short)(u >> 16);
}
__device__ __forceinline__ float bf2f(unsigned short b) {
    unsigned int u = ((unsigned int)b) << 16;
    return __builtin_bit_cast(float, u);
}

// ---------------------------------------------------------------- init: cast-transpose W; zero dummy hs row
__global__ __launch_bounds__(256) void k_init(const float* __restrict__ W,
                                              unsigned short* __restrict__ wt,
                                              unsigned short* __restrict__ hs) {
    int i = blockIdx.x * 256 + threadIdx.x;
    wt[i] = f2bf(W[(i & 127) * C + (i >> 7)]);   // wt[c][k] = W[k][c]
    if (i < C) hs[(size_t)N_NODES * C + i] = 0;  // zero row for tail gathers
}

// ---------------------------------------------------------------- coarse histogram
__global__ __launch_bounds__(256) void k_coarse(const int* __restrict__ dst,
                                                int* __restrict__ blk_cnt) {
    __shared__ int lh[NB_C];
    int tid = threadIdx.x, blk = blockIdx.x;
    for (int i = tid; i < NB_C; i += 256) lh[i] = 0;
    __syncthreads();
    #pragma unroll
    for (int it = 0; it < PBLK / 256; ++it) {
        int e = blk * PBLK + it * 256 + tid;
        if (e < N_EDGES) atomicAdd(&lh[dst[e] >> 8], 1);
    }
    __syncthreads();
    for (int i = tid; i < NB_C; i += 256) blk_cnt[i * PB + blk] = lh[i];
}

// ---------------------------------------------------------------- per-bucket exclusive scan over blocks
__global__ __launch_bounds__(512) void k_offsets(const int* __restrict__ blk_cnt,
                                                 int* __restrict__ offset,
                                                 int* __restrict__ total) {
    __shared__ int tmp[512];
    int t = threadIdx.x, k = blockIdx.x;
    int v = (t < PB) ? blk_cnt[k * PB + t] : 0;
    tmp[t] = v;
    __syncthreads();
    for (int off = 1; off < 512; off <<= 1) {
        int u = (t >= off) ? tmp[t - off] : 0;
        __syncthreads();
        tmp[t] += u;
        __syncthreads();
    }
    if (t < PB) offset[k * PB + t] = tmp[t] - v;
    if (t == 511) total[k] = tmp[511];
}

// ---------------------------------------------------------------- bucket-base scan (1 block)
__global__ __launch_bounds__(512) void k_cbase(const int* __restrict__ total,
                                               int* __restrict__ cbase,
                                               int* __restrict__ offs) {
    __shared__ int tmp[512];
    int t = threadIdx.x;
    int v = (t < NB_C) ? total[t] : 0;
    tmp[t] = v;
    __syncthreads();
    for (int off = 1; off < 512; off <<= 1) {
        int u = (t >= off) ? tmp[t - off] : 0;
        __syncthreads();
        tmp[t] += u;
        __syncthreads();
    }
    if (t < NB_C) cbase[t] = tmp[t] - v;
    if (t == 0) { cbase[NB_C] = N_EDGES; offs[N_NODES] = N_EDGES; }
}

// ---------------------------------------------------------------- partition: packed (src | dlow<<17)
__global__ __launch_bounds__(256) void k_partition(const int* __restrict__ src,
                                                   const int* __restrict__ dst,
                                                   const int* __restrict__ cbase,
                                                   const int* __restrict__ offset,
                                                   unsigned int* __restrict__ pairs) {
    __shared__ int lh[NB_C];
    __shared__ int lbase[NB_C];
    int tid = threadIdx.x, blk = blockIdx.x;
    for (int i = tid; i < NB_C; i += 256) {
        lh[i] = 0;
        lbase[i] = cbase[i] + offset[i * PB + blk];
    }
    __syncthreads();
    #pragma unroll
    for (int it = 0; it < PBLK / 256; ++it) {
        int e = blk * PBLK + it * 256 + tid;
        if (e < N_EDGES) {
            int d = dst[e];
            int b = d >> 8;
            int r = atomicAdd(&lh[b], 1);
            pairs[lbase[b] + r] = (unsigned int)src[e] | ((unsigned int)(d & 255) << 17);
        }
    }
}

// ---------------------------------------------------------------- fine: hist -> dinv+offs; LDS-rank -> srt
__global__ __launch_bounds__(256) void k_fine(const unsigned int* __restrict__ pairs,
                                              const int* __restrict__ cbase,
                                              float* __restrict__ dinv,
                                              int* __restrict__ offs,
                                              int* __restrict__ srt) {
    __shared__ int hist[256];
    __shared__ int loff[256];
    __shared__ int cnt2[256];
    __shared__ unsigned int stash[STASH];
    int tid = threadIdx.x, blk = blockIdx.x;
    int nbase = blk * 256;
    int nn = (nbase + 256 <= N_NODES) ? 256 : (N_NODES - nbase);
    int ebeg = cbase[blk];
    int ne = cbase[blk + 1] - ebeg;

    hist[tid] = 0; cnt2[tid] = 0;
    __syncthreads();
    for (int k = tid; k < ne; k += 256) {
        unsigned int pk = pairs[ebeg + k];
        if (k < STASH) stash[k] = pk;
        atomicAdd(&hist[pk >> 17], 1);
    }
    __syncthreads();
    if (tid < nn) dinv[nbase + tid] = rsqrtf((float)(hist[tid] + 1));
    loff[tid] = hist[tid];
    __syncthreads();
    for (int off = 1; off < 256; off <<= 1) {
        int u = (tid >= off) ? loff[tid - off] : 0;
        __syncthreads();
        loff[tid] += u;
        __syncthreads();
    }
    loff[tid] -= hist[tid];           // exclusive
    if (tid < nn) offs[nbase + tid] = ebeg + loff[tid];
    __syncthreads();
    for (int k = tid; k < ne; k += 256) {
        unsigned int pk = (k < STASH) ? stash[k] : pairs[ebeg + k];
        int dl = pk >> 17;
        int r = atomicAdd(&cnt2[dl], 1);
        srt[ebeg + loff[dl] + r] = (int)(pk & 0x1FFFFu);
    }
}

// ---------------------------------------------------------------- gemm: hs = bf16((x @ W) * dinv[row]), in-reg cast
__global__ __launch_bounds__(256) void k_gemm_hs(const float* __restrict__ x,
                                                 const unsigned short* __restrict__ wt,
                                                 const float* __restrict__ dinv,
                                                 unsigned short* __restrict__ hs) {
    int tile = blockIdx.x * 4 + (threadIdx.x >> 6);
    if (tile >= N_NODES / 16) return;
    int lane = threadIdx.x & 63;
    int row0 = tile * 16;
    int ar = lane & 15;
    int kg = (lane >> 4) * 8;

    short8 a[4];
    #pragma unroll
    for (int kk = 0; kk < 4; ++kk) {
        const float* p = &x[(size_t)(row0 + ar) * C + kk * 32 + kg];
        float4 p0 = *(const float4*)p;
        float4 p1 = *(const float4*)(p + 4);
        short8 av;
        av[0] = (short)f2bf(p0.x); av[1] = (short)f2bf(p0.y);
        av[2] = (short)f2bf(p0.z); av[3] = (short)f2bf(p0.w);
        av[4] = (short)f2bf(p1.x); av[5] = (short)f2bf(p1.y);
        av[6] = (short)f2bf(p1.z); av[7] = (short)f2bf(p1.w);
        a[kk] = av;
    }

    int rb = (lane >> 4) * 4;
    float dv[4];
    #pragma unroll
    for (int r = 0; r < 4; ++r) dv[r] = dinv[row0 + rb + r];

    #pragma unroll
    for (int ct = 0; ct < 8; ++ct) {
        f32x4 acc = {0.f, 0.f, 0.f, 0.f};
        #pragma unroll
        for (int kk = 0; kk < 4; ++kk) {
            short8 b = *(const short8*)&wt[(size_t)(ct * 16 + ar) * C + kk * 32 + kg];
            acc = __builtin_amdgcn_mfma_f32_16x16x32_bf16(a[kk], b, acc, 0, 0, 0);
        }
        int col = ct * 16 + ar;          // C/D: col=lane&15, row=(lane>>4)*4+r
        #pragma unroll
        for (int r = 0; r < 4; ++r)
            hs[(size_t)(row0 + rb + r) * C + col] = f2bf(acc[r] * dv[r]);
    }
}

// ---------------------------------------------------------------- aggregate: v = leaky(dn*(hs[d]+sum hs[s]) + bias)
// writes vb bf16 + per-block BN partials (deterministic LDS tree)
__global__ __launch_bounds__(256) void k_aggregate(const short8* __restrict__ hs8,
                                                   const int* __restrict__ srt,
                                                   const int* __restrict__ offs,
                                                   const float* __restrict__ dinv,
                                                   const float* __restrict__ bias,
                                                   short8* __restrict__ vb8,
                                                   float* __restrict__ part) {
    __shared__ float lsv[16][C + 4];
    int tid = threadIdx.x;
    int g = tid >> 4, c8 = tid & 15;
    int node = blockIdx.x * 16 + g;        // N_NODES % 16 == 0

    float dn = dinv[node];
    int beg = offs[node];
    int end = offs[node + 1];

    short8 ms = hs8[(size_t)node * 16 + c8];
    float ax[8];
    #pragma unroll
    for (int ch = 0; ch < 8; ++ch) ax[ch] = bf2f((unsigned short)ms[ch]);

    for (int k = beg; k < end; k += 8) {
        int idx[8];
        #pragma unroll
        for (int i = 0; i < 8; ++i) {
            int ki = k + i;
            idx[i] = (ki < end) ? srt[ki] : N_NODES;   // dummy zero row
        }
        short8 m[8];
        #pragma unroll
        for (int i = 0; i < 8; ++i) m[i] = hs8[(size_t)idx[i] * 16 + c8];
        #pragma unroll
        for (int i = 0; i < 8; ++i)
            #pragma unroll
            for (int ch = 0; ch < 8; ++ch)
                ax[ch] += bf2f((unsigned short)m[i][ch]);
    }

    float4 b0 = *(const float4*)&bias[c8 * 8];
    float4 b1 = *(const float4*)&bias[c8 * 8 + 4];
    float bb[8] = {b0.x, b0.y, b0.z, b0.w, b1.x, b1.y, b1.z, b1.w};

    short8 o;
    #pragma unroll
    for (int ch = 0; ch < 8; ++ch) {
        float v = dn * ax[ch] + bb[ch];
        v = v > 0.0f ? v : LEAKY * v;
        o[ch] = (short)f2bf(v);
        lsv[g][c8 * 8 + ch] = v;
    }
    vb8[(size_t)node * 16 + c8] = o;

    __syncthreads();
    if (tid < C) {
        float s = 0.0f, q = 0.0f;
        #pragma unroll
        for (int g2 = 0; g2 < 16; ++g2) {
            float t = lsv[g2][tid];
            s += t; q += t * t;
        }
        part[(size_t)blockIdx.x * 256 + tid]     = s;
        part[(size_t)blockIdx.x * 256 + C + tid] = q;
    }
}

// ---------------------------------------------------------------- reduce partials: 6250 rows -> 64 rows
__global__ __launch_bounds__(256) void k_reduce(const float* __restrict__ part,
                                                float* __restrict__ part2) {
    int t = threadIdx.x, b = blockIdx.x;   // 64 blocks x 256 slots
    float s = 0.0f;
    for (int r = b; r < NAGG; r += NRED) s += part[(size_t)r * 256 + t];
    part2[(size_t)b * 256 + t] = s;
}

// ---------------------------------------------------------------- params: final reduce + fold BN scale/shift
__global__ __launch_bounds__(256) void k_params(const float* __restrict__ part2,
                                                const float* __restrict__ gamma,
                                                const float* __restrict__ beta,
                                                float* __restrict__ scale,
                                                float* __restrict__ shift) {
    __shared__ float tot[256];
    int t = threadIdx.x;
    float s = 0.0f;
    #pragma unroll
    for (int b = 0; b < NRED; ++b) s += part2[(size_t)b * 256 + t];
    tot[t] = s;
    __syncthreads();
    if (t < C) {
        float inv_n = 1.0f / (float)N_NODES;
        float mean = tot[t] * inv_n;
        float var = tot[C + t] * inv_n - mean * mean;
        float sc = gamma[t] * rsqrtf(var + BN_EPS);
        scale[t] = sc;
        shift[t] = beta[t] - mean * sc;
    }
}

// ---------------------------------------------------------------- apply: out = vb*scale + shift (bf16 -> f32)
__global__ __launch_bounds__(256) void k_apply(const short8* __restrict__ vb8,
                                               const float* __restrict__ scale,
                                               const float* __restrict__ shift,
                                               float* __restrict__ out) {
    int i = blockIdx.x * 256 + threadIdx.x;   // short8 index, N*C/8 total
    int c8 = i & 15;
    short8 v = vb8[i];
    float4 sc0 = *(const float4*)&scale[c8 * 8];
    float4 sc1 = *(const float4*)&scale[c8 * 8 + 4];
    float4 sh0 = *(const float4*)&shift[c8 * 8];
    float4 sh1 = *(const float4*)&shift[c8 * 8 + 4];
    float4 o0, o1;
    o0.x = bf2f((unsigned short)v[0]) * sc0.x + sh0.x;
    o0.y = bf2f((unsigned short)v[1]) * sc0.y + sh0.y;
    o0.z = bf2f((unsigned short)v[2]) * sc0.z + sh0.z;
    o0.w = bf2f((unsigned short)v[3]) * sc0.w + sh0.w;
    o1.x = bf2f((unsigned short)v[4]) * sc1.x + sh1.x;
    o1.y = bf2f((unsigned short)v[5]) * sc1.y + sh1.y;
    o1.z = bf2f((unsigned short)v[6]) * sc1.z + sh1.z;
    o1.w = bf2f((unsigned short)v[7]) * sc1.w + sh1.w;
    float4* op = (float4*)out + (size_t)i * 2;
    op[0] = o0;
    op[1] = o1;
}

extern "C" void kernel_launch(void* const* d_in, const int* in_sizes, int n_in,
                              void* d_out, int out_size, void* d_ws, size_t ws_size,
                              hipStream_t stream) {
    const float* x     = (const float*)d_in[0];
    const int*   edge  = (const int*)d_in[1];
    const float* W     = (const float*)d_in[2];
    const float* bias  = (const float*)d_in[3];
    const float* gamma = (const float*)d_in[4];
    const float* beta  = (const float*)d_in[5];
    float* out = (float*)d_out;
    char* ws = (char*)d_ws;

    // workspace layout (~66 MB; part aliases dead pairs)
    unsigned short* hs    = (unsigned short*)ws;  ws += (size_t)(N_NODES + 1) * C * 2; // 25.6 MB (+zero row)
    unsigned short* vb    = (unsigned short*)ws;  ws += (size_t)N_NODES * C * 2;       // 25.6 MB
    unsigned short* wt    = (unsigned short*)ws;  ws += (size_t)C * C * 2;             // 32 KB
    unsigned int*   pairs = (unsigned int*)ws;    ws += (size_t)N_EDGES * 4;           // 6.4 MB (also 'part')
    int*   srt     = (int*)ws;                    ws += (size_t)N_EDGES * 4;           // 6.4 MB
    int*   blk_cnt = (int*)ws;                    ws += (size_t)NB_C * PB * 4;         // 612 KB
    int*   offset  = (int*)ws;                    ws += (size_t)NB_C * PB * 4;         // 612 KB
    int*   total   = (int*)ws;                    ws += 512 * 4;
    int*   cbase   = (int*)ws;                    ws += 512 * 4;
    int*   offs    = (int*)ws;                    ws += (size_t)(N_NODES + 1) * 4;     // 400 KB
    float* dinv    = (float*)ws;                  ws += (size_t)N_NODES * 4;           // 400 KB
    float* part2   = (float*)ws;                  ws += (size_t)NRED * 256 * 4;        // 64 KB
    float* scale   = (float*)ws;                  ws += C * 4;
    float* shift   = (float*)ws;

    float* part = (float*)pairs;   // alias: pairs dead after k_fine, part needs 6.4 MB

    const int* src = edge;
    const int* dst = edge + N_EDGES;

    k_init     <<<C * C / 256,           256, 0, stream>>>(W, wt, hs);
    k_coarse   <<<PB,                    256, 0, stream>>>(dst, blk_cnt);
    k_offsets  <<<NB_C,                  512, 0, stream>>>(blk_cnt, offset, total);
    k_cbase    <<<1,                     512, 0, stream>>>(total, cbase, offs);
    k_partition<<<PB,                    256, 0, stream>>>(src, dst, cbase, offset, pairs);
    k_fine     <<<NB_C,                  256, 0, stream>>>(pairs, cbase, dinv, offs, srt);
    k_gemm_hs  <<<NBG,                   256, 0, stream>>>(x, wt, dinv, hs);
    k_aggregate<<<NAGG,                  256, 0, stream>>>((const short8*)hs, srt, offs, dinv, bias, (short8*)vb, part);
    k_reduce   <<<NRED,                  256, 0, stream>>>(part, part2);
    k_params   <<<1,                     256, 0, stream>>>(part2, gamma, beta, scale, shift);
    k_apply    <<<N_NODES * C / 8 / 256, 256, 0, stream>>>((const short8*)vb, scale, shift, out);
}

// Round 13
// 189.185 us; speedup vs baseline: 1.3639x; 1.0286x over previous
//
#include <hip/hip_runtime.h>

#define N_NODES 100000
#define N_EDGES 1600000
#define C 128
#define LEAKY 0.01f
#define BN_EPS 1e-5f
#define NB_C 391           // coarse buckets (dst>>8), 256 nodes each
#define PB 391             // partition blocks
#define PBLK 4096          // edges per partition block
#define STASH 8192         // fine-kernel LDS pair stash (avg bucket = 4092)
#define NBG 1563           // gemm blocks = ceil(6250 tiles / 4)
#define NAGG 6250          // aggregate blocks (16 nodes each)
#define NRED 64            // reduce blocks

typedef __attribute__((ext_vector_type(8))) short short8;   // 8 bf16 = 16B
typedef __attribute__((ext_vector_type(4))) float f32x4;

__device__ __forceinline__ unsigned short f2bf(float f) {   // RNE float->bf16
    unsigned int u = __builtin_bit_cast(unsigned int, f);
    u += 0x7FFFu + ((u >> 16) & 1u);
    return (unsigned short)(u >> 16);
}
__device__ __forceinline__ float bf2f(unsigned short b) {
    unsigned int u = ((unsigned int)b) << 16;
    return __builtin_bit_cast(float, u);
}

// ---------------------------------------------------------------- coarse histogram (+ fused init: wt cast, zero row)
__global__ __launch_bounds__(256) void k_coarse(const int* __restrict__ dst,
                                                int* __restrict__ blk_cnt,
                                                const float* __restrict__ W,
                                                unsigned short* __restrict__ wt,
                                                unsigned short* __restrict__ hs) {
    __shared__ int lh[NB_C];
    int tid = threadIdx.x, blk = blockIdx.x;
    int gi = blk * 256 + tid;
    if (gi < C * C) wt[gi] = f2bf(W[(gi & 127) * C + (gi >> 7)]);   // wt[c][k] = W[k][c]
    if (gi < C) hs[(size_t)N_NODES * C + gi] = 0;                   // zero row for tail gathers
    for (int i = tid; i < NB_C; i += 256) lh[i] = 0;
    __syncthreads();
    #pragma unroll
    for (int it = 0; it < PBLK / 256; ++it) {
        int e = blk * PBLK + it * 256 + tid;
        if (e < N_EDGES) atomicAdd(&lh[dst[e] >> 8], 1);
    }
    __syncthreads();
    for (int i = tid; i < NB_C; i += 256) blk_cnt[i * PB + blk] = lh[i];
}

// ---------------------------------------------------------------- per-bucket exclusive scan over blocks
__global__ __launch_bounds__(512) void k_offsets(const int* __restrict__ blk_cnt,
                                                 int* __restrict__ offset,
                                                 int* __restrict__ total) {
    __shared__ int tmp[512];
    int t = threadIdx.x, k = blockIdx.x;
    int v = (t < PB) ? blk_cnt[k * PB + t] : 0;
    tmp[t] = v;
    __syncthreads();
    for (int off = 1; off < 512; off <<= 1) {
        int u = (t >= off) ? tmp[t - off] : 0;
        __syncthreads();
        tmp[t] += u;
        __syncthreads();
    }
    if (t < PB) offset[k * PB + t] = tmp[t] - v;
    if (t == 511) total[k] = tmp[511];
}

// ---------------------------------------------------------------- bucket-base scan (1 block)
__global__ __launch_bounds__(512) void k_cbase(const int* __restrict__ total,
                                               int* __restrict__ cbase,
                                               int* __restrict__ offs) {
    __shared__ int tmp[512];
    int t = threadIdx.x;
    int v = (t < NB_C) ? total[t] : 0;
    tmp[t] = v;
    __syncthreads();
    for (int off = 1; off < 512; off <<= 1) {
        int u = (t >= off) ? tmp[t - off] : 0;
        __syncthreads();
        tmp[t] += u;
        __syncthreads();
    }
    if (t < NB_C) cbase[t] = tmp[t] - v;
    if (t == 0) { cbase[NB_C] = N_EDGES; offs[N_NODES] = N_EDGES; }
}

// ---------------------------------------------------------------- partition: packed (src | dlow<<17)
__global__ __launch_bounds__(256) void k_partition(const int* __restrict__ src,
                                                   const int* __restrict__ dst,
                                                   const int* __restrict__ cbase,
                                                   const int* __restrict__ offset,
                                                   unsigned int* __restrict__ pairs) {
    __shared__ int lh[NB_C];
    __shared__ int lbase[NB_C];
    int tid = threadIdx.x, blk = blockIdx.x;
    for (int i = tid; i < NB_C; i += 256) {
        lh[i] = 0;
        lbase[i] = cbase[i] + offset[i * PB + blk];
    }
    __syncthreads();
    #pragma unroll
    for (int it = 0; it < PBLK / 256; ++it) {
        int e = blk * PBLK + it * 256 + tid;
        if (e < N_EDGES) {
            int d = dst[e];
            int b = d >> 8;
            int r = atomicAdd(&lh[b], 1);
            pairs[lbase[b] + r] = (unsigned int)src[e] | ((unsigned int)(d & 255) << 17);
        }
    }
}

// ---------------------------------------------------------------- fine: hist -> dinv+offs; LDS-rank -> srt
__global__ __launch_bounds__(256) void k_fine(const unsigned int* __restrict__ pairs,
                                              const int* __restrict__ cbase,
                                              float* __restrict__ dinv,
                                              int* __restrict__ offs,
                                              int* __restrict__ srt) {
    __shared__ int hist[256];
    __shared__ int loff[256];
    __shared__ int cnt2[256];
    __shared__ unsigned int stash[STASH];
    int tid = threadIdx.x, blk = blockIdx.x;
    int nbase = blk * 256;
    int nn = (nbase + 256 <= N_NODES) ? 256 : (N_NODES - nbase);
    int ebeg = cbase[blk];
    int ne = cbase[blk + 1] - ebeg;

    hist[tid] = 0; cnt2[tid] = 0;
    __syncthreads();
    for (int k = tid; k < ne; k += 256) {
        unsigned int pk = pairs[ebeg + k];
        if (k < STASH) stash[k] = pk;
        atomicAdd(&hist[pk >> 17], 1);
    }
    __syncthreads();
    if (tid < nn) dinv[nbase + tid] = rsqrtf((float)(hist[tid] + 1));
    loff[tid] = hist[tid];
    __syncthreads();
    for (int off = 1; off < 256; off <<= 1) {
        int u = (tid >= off) ? loff[tid - off] : 0;
        __syncthreads();
        loff[tid] += u;
        __syncthreads();
    }
    loff[tid] -= hist[tid];           // exclusive
    if (tid < nn) offs[nbase + tid] = ebeg + loff[tid];
    __syncthreads();
    for (int k = tid; k < ne; k += 256) {
        unsigned int pk = (k < STASH) ? stash[k] : pairs[ebeg + k];
        int dl = pk >> 17;
        int r = atomicAdd(&cnt2[dl], 1);
        srt[ebeg + loff[dl] + r] = (int)(pk & 0x1FFFFu);
    }
}

// ---------------------------------------------------------------- gemm: hs = bf16((x @ W) * dinv[row]), in-reg cast
__global__ __launch_bounds__(256) void k_gemm_hs(const float* __restrict__ x,
                                                 const unsigned short* __restrict__ wt,
                                                 const float* __restrict__ dinv,
                                                 unsigned short* __restrict__ hs) {
    int tile = blockIdx.x * 4 + (threadIdx.x >> 6);
    if (tile >= N_NODES / 16) return;
    int lane = threadIdx.x & 63;
    int row0 = tile * 16;
    int ar = lane & 15;
    int kg = (lane >> 4) * 8;

    short8 a[4];
    #pragma unroll
    for (int kk = 0; kk < 4; ++kk) {
        const float* p = &x[(size_t)(row0 + ar) * C + kk * 32 + kg];
        float4 p0 = *(const float4*)p;
        float4 p1 = *(const float4*)(p + 4);
        short8 av;
        av[0] = (short)f2bf(p0.x); av[1] = (short)f2bf(p0.y);
        av[2] = (short)f2bf(p0.z); av[3] = (short)f2bf(p0.w);
        av[4] = (short)f2bf(p1.x); av[5] = (short)f2bf(p1.y);
        av[6] = (short)f2bf(p1.z); av[7] = (short)f2bf(p1.w);
        a[kk] = av;
    }

    int rb = (lane >> 4) * 4;
    float dv[4];
    #pragma unroll
    for (int r = 0; r < 4; ++r) dv[r] = dinv[row0 + rb + r];

    #pragma unroll
    for (int ct = 0; ct < 8; ++ct) {
        f32x4 acc = {0.f, 0.f, 0.f, 0.f};
        #pragma unroll
        for (int kk = 0; kk < 4; ++kk) {
            short8 b = *(const short8*)&wt[(size_t)(ct * 16 + ar) * C + kk * 32 + kg];
            acc = __builtin_amdgcn_mfma_f32_16x16x32_bf16(a[kk], b, acc, 0, 0, 0);
        }
        int col = ct * 16 + ar;          // C/D: col=lane&15, row=(lane>>4)*4+r
        #pragma unroll
        for (int r = 0; r < 4; ++r)
            hs[(size_t)(row0 + rb + r) * C + col] = f2bf(acc[r] * dv[r]);
    }
}

// ---------------------------------------------------------------- aggregate: ONE NODE PER WAVE, lane = 2 channels (u32)
// v = leaky(dn*(hs[d]+sum hs[s]) + bias); vb bf16 + per-block BN partials
__global__ __launch_bounds__(256) void k_aggregate(const unsigned int* __restrict__ hs32,
                                                   const int* __restrict__ srt,
                                                   const int* __restrict__ offs,
                                                   const float* __restrict__ dinv,
                                                   const float* __restrict__ bias,
                                                   unsigned int* __restrict__ vb32,
                                                   float* __restrict__ part) {
    __shared__ float red_s[4][C];
    __shared__ float red_q[4][C];
    int wave = threadIdx.x >> 6, lane = threadIdx.x & 63;
    float2 bb = ((const float2*)bias)[lane];      // channels 2*lane, 2*lane+1
    float s0 = 0.f, s1 = 0.f, q0 = 0.f, q1 = 0.f;

    #pragma unroll
    for (int g = 0; g < 4; ++g) {
        int node = __builtin_amdgcn_readfirstlane(blockIdx.x * 16 + g * 4 + wave);
        float dn = dinv[node];
        int beg = offs[node];
        int end = offs[node + 1];

        unsigned int ms = hs32[(size_t)node * 64 + lane];
        float ax0 = __builtin_bit_cast(float, ms << 16);
        float ax1 = __builtin_bit_cast(float, ms & 0xFFFF0000u);

        for (int k = beg; k < end; k += 8) {
            int idx[8];
            #pragma unroll
            for (int i = 0; i < 8; ++i) {
                int ki = k + i;
                idx[i] = (ki < end) ? srt[ki] : N_NODES;   // dummy zero row
            }
            unsigned int m[8];
            #pragma unroll
            for (int i = 0; i < 8; ++i) m[i] = hs32[(size_t)idx[i] * 64 + lane];
            #pragma unroll
            for (int i = 0; i < 8; ++i) {
                ax0 += __builtin_bit_cast(float, m[i] << 16);
                ax1 += __builtin_bit_cast(float, m[i] & 0xFFFF0000u);
            }
        }

        float v0 = dn * ax0 + bb.x; v0 = v0 > 0.f ? v0 : LEAKY * v0;
        float v1 = dn * ax1 + bb.y; v1 = v1 > 0.f ? v1 : LEAKY * v1;
        vb32[(size_t)node * 64 + lane] =
            (unsigned int)f2bf(v0) | ((unsigned int)f2bf(v1) << 16);
        s0 += v0; q0 += v0 * v0;
        s1 += v1; q1 += v1 * v1;
    }

    red_s[wave][lane * 2] = s0;  red_s[wave][lane * 2 + 1] = s1;
    red_q[wave][lane * 2] = q0;  red_q[wave][lane * 2 + 1] = q1;
    __syncthreads();
    int tid = threadIdx.x;
    if (tid < C) {
        part[(size_t)blockIdx.x * 256 + tid] =
            red_s[0][tid] + red_s[1][tid] + red_s[2][tid] + red_s[3][tid];
    } else {
        int c = tid - C;
        part[(size_t)blockIdx.x * 256 + tid] =
            red_q[0][c] + red_q[1][c] + red_q[2][c] + red_q[3][c];
    }
}

// ---------------------------------------------------------------- reduce partials: 6250 rows -> 64 rows
__global__ __launch_bounds__(256) void k_reduce(const float* __restrict__ part,
                                                float* __restrict__ part2) {
    int t = threadIdx.x, b = blockIdx.x;   // 64 blocks x 256 slots
    float s = 0.0f;
    for (int r = b; r < NAGG; r += NRED) s += part[(size_t)r * 256 + t];
    part2[(size_t)b * 256 + t] = s;
}

// ---------------------------------------------------------------- params: final reduce + fold BN scale/shift
__global__ __launch_bounds__(256) void k_params(const float* __restrict__ part2,
                                                const float* __restrict__ gamma,
                                                const float* __restrict__ beta,
                                                float* __restrict__ scale,
                                                float* __restrict__ shift) {
    __shared__ float tot[256];
    int t = threadIdx.x;
    float s = 0.0f;
    #pragma unroll
    for (int b = 0; b < NRED; ++b) s += part2[(size_t)b * 256 + t];
    tot[t] = s;
    __syncthreads();
    if (t < C) {
        float inv_n = 1.0f / (float)N_NODES;
        float mean = tot[t] * inv_n;
        float var = tot[C + t] * inv_n - mean * mean;
        float sc = gamma[t] * rsqrtf(var + BN_EPS);
        scale[t] = sc;
        shift[t] = beta[t] - mean * sc;
    }
}

// ---------------------------------------------------------------- apply: out = vb*scale + shift (bf16 -> f32)
__global__ __launch_bounds__(256) void k_apply(const short8* __restrict__ vb8,
                                               const float* __restrict__ scale,
                                               const float* __restrict__ shift,
                                               float* __restrict__ out) {
    int i = blockIdx.x * 256 + threadIdx.x;   // short8 index, N*C/8 total
    int c8 = i & 15;
    short8 v = vb8[i];
    float4 sc0 = *(const float4*)&scale[c8 * 8];
    float4 sc1 = *(const float4*)&scale[c8 * 8 + 4];
    float4 sh0 = *(const float4*)&shift[c8 * 8];
    float4 sh1 = *(const float4*)&shift[c8 * 8 + 4];
    float4 o0, o1;
    o0.x = bf2f((unsigned short)v[0]) * sc0.x + sh0.x;
    o0.y = bf2f((unsigned short)v[1]) * sc0.y + sh0.y;
    o0.z = bf2f((unsigned short)v[2]) * sc0.z + sh0.z;
    o0.w = bf2f((unsigned short)v[3]) * sc0.w + sh0.w;
    o1.x = bf2f((unsigned short)v[4]) * sc1.x + sh1.x;
    o1.y = bf2f((unsigned short)v[5]) * sc1.y + sh1.y;
    o1.z = bf2f((unsigned short)v[6]) * sc1.z + sh1.z;
    o1.w = bf2f((unsigned short)v[7]) * sc1.w + sh1.w;
    float4* op = (float4*)out + (size_t)i * 2;
    op[0] = o0;
    op[1] = o1;
}

extern "C" void kernel_launch(void* const* d_in, const int* in_sizes, int n_in,
                              void* d_out, int out_size, void* d_ws, size_t ws_size,
                              hipStream_t stream) {
    const float* x     = (const float*)d_in[0];
    const int*   edge  = (const int*)d_in[1];
    const float* W     = (const float*)d_in[2];
    const float* bias  = (const float*)d_in[3];
    const float* gamma = (const float*)d_in[4];
    const float* beta  = (const float*)d_in[5];
    float* out = (float*)d_out;
    char* ws = (char*)d_ws;

    // workspace layout (~66 MB; part aliases dead pairs)
    unsigned short* hs    = (unsigned short*)ws;  ws += (size_t)(N_NODES + 1) * C * 2; // 25.6 MB (+zero row)
    unsigned short* vb    = (unsigned short*)ws;  ws += (size_t)N_NODES * C * 2;       // 25.6 MB
    unsigned short* wt    = (unsigned short*)ws;  ws += (size_t)C * C * 2;             // 32 KB
    unsigned int*   pairs = (unsigned int*)ws;    ws += (size_t)N_EDGES * 4;           // 6.4 MB (also 'part')
    int*   srt     = (int*)ws;                    ws += (size_t)N_EDGES * 4;           // 6.4 MB
    int*   blk_cnt = (int*)ws;                    ws += (size_t)NB_C * PB * 4;         // 612 KB
    int*   offset  = (int*)ws;                    ws += (size_t)NB_C * PB * 4;         // 612 KB
    int*   total   = (int*)ws;                    ws += 512 * 4;
    int*   cbase   = (int*)ws;                    ws += 512 * 4;
    int*   offs    = (int*)ws;                    ws += (size_t)(N_NODES + 1) * 4;     // 400 KB
    float* dinv    = (float*)ws;                  ws += (size_t)N_NODES * 4;           // 400 KB
    float* part2   = (float*)ws;                  ws += (size_t)NRED * 256 * 4;        // 64 KB
    float* scale   = (float*)ws;                  ws += C * 4;
    float* shift   = (float*)ws;

    float* part = (float*)pairs;   // alias: pairs dead after k_fine

    const int* src = edge;
    const int* dst = edge + N_EDGES;

    k_coarse   <<<PB,                    256, 0, stream>>>(dst, blk_cnt, W, wt, hs);
    k_offsets  <<<NB_C,                  512, 0, stream>>>(blk_cnt, offset, total);
    k_cbase    <<<1,                     512, 0, stream>>>(total, cbase, offs);
    k_partition<<<PB,                    256, 0, stream>>>(src, dst, cbase, offset, pairs);
    k_fine     <<<NB_C,                  256, 0, stream>>>(pairs, cbase, dinv, offs, srt);
    k_gemm_hs  <<<NBG,                   256, 0, stream>>>(x, wt, dinv, hs);
    k_aggregate<<<NAGG,                  256, 0, stream>>>((const unsigned int*)hs, srt, offs, dinv, bias,
                                                           (unsigned int*)vb, part);
    k_reduce   <<<NRED,                  256, 0, stream>>>(part, part2);
    k_params   <<<1,                     256, 0, stream>>>(part2, gamma, beta, scale, shift);
    k_apply    <<<N_NODES * C / 8 / 256, 256, 0, stream>>>((const short8*)vb, scale, shift, out);
}